// Round 6
// baseline (1917.719 us; speedup 1.0000x reference)
//
#include <hip/hip_runtime.h>

// Problem constants (fixed shape)
// N=8192 tokens, D=1280, H=16 heads, K=80 head dim (pad 96), S=16 segs, L=512
#define LOG2E 1.44269504088896340736f
#define ATT_SCALE 0.11180339887498949f  // 80^-0.5

typedef _Float16 half8 __attribute__((ext_vector_type(8)));
typedef _Float16 half4v __attribute__((ext_vector_type(4)));
typedef __fp16 fp16x2 __attribute__((ext_vector_type(2)));
typedef float f32x4 __attribute__((ext_vector_type(4)));

#define MFMA(a, b, c) __builtin_amdgcn_mfma_f32_16x16x32_f16((a), (b), (c), 0, 0, 0)

__device__ __forceinline__ void async16(const _Float16* g, _Float16* l) {
  __builtin_amdgcn_global_load_lds(
      (const __attribute__((address_space(1))) unsigned int*)g,
      (__attribute__((address_space(3))) unsigned int*)l,
      16, 0, 0);
}

// ---------------- fp32 -> fp16 convert (hidden) ----------------
__global__ __launch_bounds__(256) void cvt_k(const float* __restrict__ in,
                                             _Float16* __restrict__ out, int n4) {
  int i = blockIdx.x * 256 + threadIdx.x;
  if (i < n4) {
    f32x4 v = ((const f32x4*)in)[i];
    half4v hv;
    hv[0] = (_Float16)v[0]; hv[1] = (_Float16)v[1];
    hv[2] = (_Float16)v[2]; hv[3] = (_Float16)v[3];
    ((half4v*)out)[i] = hv;
  }
}

// ---------------- transpose + convert: in R x C fp32 -> out C x R fp16 ----------
__global__ __launch_bounds__(256) void transpose_cvt_k(const float* __restrict__ in,
                                                       _Float16* __restrict__ out,
                                                       int R, int C) {
  __shared__ float tile[32][33];
  const int tx = threadIdx.x & 31, ty = threadIdx.x >> 5;
  const int c0 = blockIdx.x * 32, r0 = blockIdx.y * 32;
#pragma unroll
  for (int i = 0; i < 32; i += 8)
    tile[ty + i][tx] = in[(size_t)(r0 + ty + i) * C + c0 + tx];
  __syncthreads();
#pragma unroll
  for (int i = 0; i < 32; i += 8)
    out[(size_t)(c0 + ty + i) * R + r0 + tx] = (_Float16)tile[tx][ty + i];
}

// ---------------- GEMM: 128x128 tile, BK=32, swizzled LDS --------------------
// launch_bounds(256,8): cap VGPR at 64 -> 8 waves/SIMD eligible (was 80 -> 6).
// acc lives in AGPR (separate budget, m97/m98 evidence). In-loop needs ~50 VGPR.
// MODE 0: scatter epilogue -> Qf/Kf (seg-head x 512 x 96), VTf (80 x 512)
// MODE 1: Out fp32 = val + bias
template <int MODE>
__global__ __launch_bounds__(256, 8) void gemm_k(const _Float16* __restrict__ A,
                                                 const _Float16* __restrict__ BT,
                                                 const float* __restrict__ bias,
                                                 _Float16* __restrict__ Qf,
                                                 _Float16* __restrict__ Kf,
                                                 _Float16* __restrict__ VTf,
                                                 float* __restrict__ Out) {
  __shared__ _Float16 sA[128 * 32];
  __shared__ _Float16 sB[128 * 32];
  const int tid = threadIdx.x;
  const int wave = tid >> 6, lane = tid & 63;
  const int quad = lane >> 4, l16 = lane & 15;
  const int m0 = blockIdx.x * 128;
  const int n0 = blockIdx.y * 128;
  const int mw = (wave & 1) * 64, nw = (wave >> 1) * 64;
  const int KD = 1280;

  // DMA source group swizzle: loop-invariant per lane
  const int srcg = (lane & 3) ^ ((lane >> 3) & 3);
  // fragment-read physical group: loop-invariant per lane
  const int rg = (quad ^ ((l16 >> 1) & 3)) * 8;

  f32x4 acc[4][4] = {};

  for (int kt = 0; kt < KD; kt += 32) {
#pragma unroll
    for (int c = 0; c < 2; ++c) {
      const int j = wave * 2 + c;
      const int row = j * 16 + (lane >> 2);
      async16(A + (size_t)(m0 + row) * KD + kt + srcg * 8, &sA[j * 512]);
      async16(BT + (size_t)(n0 + row) * KD + kt + srcg * 8, &sB[j * 512]);
    }
    __syncthreads();
    half8 af[4], bf[4];
#pragma unroll
    for (int i = 0; i < 4; ++i) {
      af[i] = *(const half8*)&sA[(mw + i * 16 + l16) * 32 + rg];
      bf[i] = *(const half8*)&sB[(nw + i * 16 + l16) * 32 + rg];
    }
#pragma unroll
    for (int i = 0; i < 4; ++i)
#pragma unroll
      for (int j2 = 0; j2 < 4; ++j2)
        acc[i][j2] = MFMA(af[i], bf[j2], acc[i][j2]);
    __syncthreads();
  }

  // epilogue: C row = (quad*4+reg), col = l16  [m89-verified]
#pragma unroll
  for (int i = 0; i < 4; ++i) {
#pragma unroll
    for (int j2 = 0; j2 < 4; ++j2) {
      const int col = n0 + nw + j2 * 16 + l16;
      const float bv = bias[col];
      const int rowb = m0 + mw + i * 16 + quad * 4;
#pragma unroll
      for (int r = 0; r < 4; ++r) {
        const float v = acc[i][j2][r] + bv;
        const int mrow = rowb + r;
        if (MODE == 0) {
          const int which = col / 1280;
          const int rem = col - which * 1280;
          const int h = rem / 80;
          const int kk = rem - h * 80;
          const int s = mrow >> 9, l = mrow & 511;
          const int shh = s * 16 + h;
          if (which == 0)
            Qf[((size_t)shh * 512 + l) * 96 + kk] = (_Float16)v;
          else if (which == 1)
            Kf[((size_t)shh * 512 + l) * 96 + kk] = (_Float16)v;
          else
            VTf[((size_t)shh * 80 + kk) * 512 + l] = (_Float16)v;
        } else {
          Out[(size_t)mrow * 1280 + col] = v;
        }
      }
    }
  }
}

// ---------------- RoPE in-place on Qf/Kf + zero the k-pad [80,96) -------------
__global__ __launch_bounds__(256) void rope_k(_Float16* __restrict__ Qf,
                                              _Float16* __restrict__ Kf,
                                              const float* __restrict__ cosNK,
                                              const float* __restrict__ sinNK) {
  const int gid = blockIdx.x * 256 + threadIdx.x;
  const int j = gid & 63;
  const int row = gid >> 6;
  const int qk = row >> 17;
  const int r = row & 131071;      // (s*16+h)*512 + l
  _Float16* buf = qk ? Kf : Qf;
  const int l = r & 511;
  const int s = r >> 13;
  const int t = s * 512 + l;
  const size_t base = (size_t)r * 96;
  if (j < 40) {
    const float v1 = (float)buf[base + j];
    const float v2 = (float)buf[base + j + 40];
    const float c1 = cosNK[t * 80 + j], s1 = sinNK[t * 80 + j];
    const float c2 = cosNK[t * 80 + j + 40], s2 = sinNK[t * 80 + j + 40];
    buf[base + j] = (_Float16)(v1 * c1 - v2 * s1);
    buf[base + j + 40] = (_Float16)(v2 * c2 + v1 * s2);
  } else if (j < 56) {
    buf[base + 40 + j] = (_Float16)0.f;  // kk = 80..95
  }
}

// ---------------- flash attention (S^T form, no-max softmax, sum via ones) ----
// block = (seg-head, 64-row q tile): 4 waves x 16 rows. BC=64, dim 80 (pad 96).
// Smaller block -> ~4 blocks/CU (LDS 35.5 KB), short critical path, good tail.
__global__ __launch_bounds__(256) void attn_k(const _Float16* __restrict__ Qf,
                                              const _Float16* __restrict__ Kf,
                                              const _Float16* __restrict__ VTf,
                                              _Float16* __restrict__ attnA) {
  __shared__ _Float16 sP[64 * 72];    // P tile, row stride 72
  __shared__ _Float16 sK[64 * 104];   // K tile, row stride 104 (conflict-free)
  __shared__ _Float16 sV[96 * 72];    // rows 0..79: V^T tile; rows 80..95: ones
  const int tid = threadIdx.x;
  const int wave = tid >> 6, lane = tid & 63;
  const int quad = lane >> 4, l16 = lane & 15;
  const int shh = blockIdx.x;  // s*16+h
  const int qt = blockIdx.y;   // 0..7 (64-row q tiles)
  const int h = shh & 15;
  const int s = shh >> 4;

  const _Float16* Qb = Qf + ((size_t)shh * 512 + qt * 64) * 96;
  const _Float16* Kb0 = Kf + (size_t)shh * 512 * 96;
  const _Float16* Vb0 = VTf + (size_t)shh * 80 * 512;

  // Q fragments straight from global (rows are lane-exact), pre-scaled
  const _Float16 c1h = (_Float16)(ATT_SCALE * LOG2E);
  half8 qf[3];
#pragma unroll
  for (int ks = 0; ks < 3; ++ks) {
    half8 t = *(const half8*)(Qb + (size_t)(wave * 16 + l16) * 96 + ks * 32 + quad * 8);
#pragma unroll
    for (int e = 0; e < 8; ++e) t[e] *= c1h;
    qf[ks] = t;
  }

  // ones rows for the row-sum trick
  for (int idx = tid; idx < 16 * 72; idx += 256) sV[80 * 72 + idx] = (_Float16)1.f;

  f32x4 o[6] = {};  // ft 0..4: output features; ft 5: row sum

  for (int kc = 0; kc < 8; ++kc) {
    __syncthreads();  // prev iter LDS reads done (iter0: ones visible)
    // K tile -> sK, padded stride 104 halves (208 B), masked DMA (13 chunks)
    const _Float16* Kb = Kb0 + (size_t)kc * 64 * 96;
#pragma unroll
    for (int c = 0; c < 4; ++c) {
      const int j = wave + 4 * c;
      if (j < 13) {
        const int off = j * 1024 + lane * 16;  // LDS byte offset
        const int krow = off / 208;
        const int kcol = off - krow * 208;     // bytes within padded row
        if (kcol < 192)
          async16(Kb + (size_t)krow * 96 + (kcol >> 1), &sK[j * 512]);
      }
    }
    // V^T tile -> sV, padded stride 72 halves (144 B), masked DMA (12 chunks)
#pragma unroll
    for (int c = 0; c < 3; ++c) {
      const int j = wave + 4 * c;
      const int off = j * 1024 + lane * 16;
      const int vrow = off / 144;
      const int colb = off - vrow * 144;
      if (vrow < 80 && colb < 128)
        async16(Vb0 + (size_t)vrow * 512 + kc * 64 + (colb >> 1), &sV[j * 512]);
    }
    __syncthreads();

    // S^T = K Q^T (operand swap): lane holds S[q=l16][k=mt*16+quad*4+r]
    f32x4 sacc[4] = {};
#pragma unroll
    for (int mt = 0; mt < 4; ++mt) {
#pragma unroll
      for (int ks = 0; ks < 3; ++ks) {
        half8 kb = *(const half8*)&sK[(mt * 16 + l16) * 104 + ks * 32 + quad * 8];
        sacc[mt] = MFMA(kb, qf[ks], sacc[mt]);
      }
    }

    // p = exp2(s), packed pairs (consecutive k!), one b64 store per mt
#pragma unroll
    for (int mt = 0; mt < 4; ++mt) {
      union { fp16x2 h2[2]; half4v h4; } u;
      u.h2[0] = __builtin_amdgcn_cvt_pkrtz(
          __builtin_amdgcn_exp2f(sacc[mt][0]),
          __builtin_amdgcn_exp2f(sacc[mt][1]));
      u.h2[1] = __builtin_amdgcn_cvt_pkrtz(
          __builtin_amdgcn_exp2f(sacc[mt][2]),
          __builtin_amdgcn_exp2f(sacc[mt][3]));
      *(half4v*)&sP[(wave * 16 + l16) * 72 + mt * 16 + quad * 4] = u.h4;
    }
    // sP rows are wave-private: per-wave LDS ordering suffices, no barrier

    // O += P V  (ft=5 accumulates the row sum via the ones rows)
#pragma unroll
    for (int ks = 0; ks < 2; ++ks) {
      half8 pa = *(const half8*)&sP[(wave * 16 + l16) * 72 + ks * 32 + quad * 8];
#pragma unroll
      for (int ft = 0; ft < 6; ++ft) {
        half8 vb = *(const half8*)&sV[(ft * 16 + l16) * 72 + ks * 32 + quad * 8];
        o[ft] = MFMA(pa, vb, o[ft]);
      }
    }
  }

  // epilogue: divide by row sum, store fp16 into attnA [token][h*80+f]
#pragma unroll
  for (int r = 0; r < 4; ++r) {
    const float inv = 1.0f / o[5][r];
    const int token = s * 512 + qt * 64 + wave * 16 + quad * 4 + r;
#pragma unroll
    for (int ft = 0; ft < 5; ++ft)
      attnA[(size_t)token * 1280 + h * 80 + ft * 16 + l16] =
          (_Float16)(o[ft][r] * inv);
  }
}

extern "C" void kernel_launch(void* const* d_in, const int* in_sizes, int n_in,
                              void* d_out, int out_size, void* d_ws, size_t ws_size,
                              hipStream_t stream) {
  (void)in_sizes; (void)n_in; (void)out_size; (void)ws_size;
  const float* hidden = (const float*)d_in[0];
  const float* cosNK = (const float*)d_in[2];
  const float* sinNK = (const float*)d_in[3];
  const float* qkv_w = (const float*)d_in[4];
  const float* qkv_b = (const float*)d_in[5];
  const float* proj_w = (const float*)d_in[6];
  const float* proj_b = (const float*)d_in[7];
  float* out = (float*)d_out;

  char* ws = (char*)d_ws;
  _Float16* hA    = (_Float16*)(ws);                   // 8192x1280        20971520 B
  _Float16* wT    = (_Float16*)(ws + 20971520);        // 3840x1280         9830400 B
  _Float16* projT = (_Float16*)(ws + 30801920);        // 1280x1280         3276800 B
  _Float16* Qf    = (_Float16*)(ws + 34078720);        // 256x512x96       25165824 B
  _Float16* Kf    = (_Float16*)(ws + 59244544);        // 256x512x96       25165824 B
  _Float16* VTf   = (_Float16*)(ws + 84410368);        // 256x80x512       20971520 B
  _Float16* attnA = (_Float16*)(ws + 105381888);       // 8192x1280        20971520 B

  cvt_k<<<10240, 256, 0, stream>>>(hidden, hA, 2621440);
  transpose_cvt_k<<<dim3(120, 40), 256, 0, stream>>>(qkv_w, wT, 1280, 3840);
  transpose_cvt_k<<<dim3(40, 40), 256, 0, stream>>>(proj_w, projT, 1280, 1280);
  gemm_k<0><<<dim3(64, 30), 256, 0, stream>>>(hA, wT, qkv_b, Qf, Kf, VTf, nullptr);
  rope_k<<<65536, 256, 0, stream>>>(Qf, Kf, cosNK, sinNK);
  attn_k<<<dim3(256, 8), 256, 0, stream>>>(Qf, Kf, VTf, attnA);
  gemm_k<1><<<dim3(64, 10), 256, 0, stream>>>(attnA, projT, proj_b, nullptr, nullptr,
                                              nullptr, out);
}

// Round 7
// 379.453 us; speedup vs baseline: 5.0539x; 5.0539x over previous
//
#include <hip/hip_runtime.h>

// Problem constants (fixed shape)
// N=8192 tokens, D=1280, H=16 heads, K=80 head dim (pad 96), S=16 segs, L=512
#define LOG2E 1.44269504088896340736f
#define ATT_SCALE 0.11180339887498949f  // 80^-0.5

typedef _Float16 half8 __attribute__((ext_vector_type(8)));
typedef _Float16 half4v __attribute__((ext_vector_type(4)));
typedef __fp16 fp16x2 __attribute__((ext_vector_type(2)));
typedef float f32x4 __attribute__((ext_vector_type(4)));

#define MFMA(a, b, c) __builtin_amdgcn_mfma_f32_16x16x32_f16((a), (b), (c), 0, 0, 0)

__device__ __forceinline__ void async16(const _Float16* g, _Float16* l) {
  __builtin_amdgcn_global_load_lds(
      (const __attribute__((address_space(1))) unsigned int*)g,
      (__attribute__((address_space(3))) unsigned int*)l,
      16, 0, 0);
}

// ---------------- fp32 -> fp16 convert (hidden) ----------------
__global__ __launch_bounds__(256) void cvt_k(const float* __restrict__ in,
                                             _Float16* __restrict__ out, int n4) {
  int i = blockIdx.x * 256 + threadIdx.x;
  if (i < n4) {
    f32x4 v = ((const f32x4*)in)[i];
    half4v hv;
    hv[0] = (_Float16)v[0]; hv[1] = (_Float16)v[1];
    hv[2] = (_Float16)v[2]; hv[3] = (_Float16)v[3];
    ((half4v*)out)[i] = hv;
  }
}

// ---------------- transpose + convert: in R x C fp32 -> out C x R fp16 ----------
__global__ __launch_bounds__(256) void transpose_cvt_k(const float* __restrict__ in,
                                                       _Float16* __restrict__ out,
                                                       int R, int C) {
  __shared__ float tile[32][33];
  const int tx = threadIdx.x & 31, ty = threadIdx.x >> 5;
  const int c0 = blockIdx.x * 32, r0 = blockIdx.y * 32;
#pragma unroll
  for (int i = 0; i < 32; i += 8)
    tile[ty + i][tx] = in[(size_t)(r0 + ty + i) * C + c0 + tx];
  __syncthreads();
#pragma unroll
  for (int i = 0; i < 32; i += 8)
    out[(size_t)(c0 + ty + i) * R + r0 + tx] = (_Float16)tile[tx][ty + i];
}

// ---------------- GEMM: 128x128 tile, BK=32, swizzled LDS --------------------
// BOUND: min waves/EU. gfx950 unified VGPR/AGPR file: acc(64 AGPR)+arch count
// together. BOUND=4 -> 128 regs/wave total = 64 arch + 64 acc (mild squeeze
// from the natural 80 arch). BOUND=8 (R6) forced acc spill -> 9x regression.
// MODE 0: scatter epilogue -> Qf/Kf (seg-head x 512 x 96), VTf (80 x 512)
// MODE 1: Out fp32 = val + bias
template <int MODE, int BOUND>
__global__ __launch_bounds__(256, BOUND) void gemm_k(const _Float16* __restrict__ A,
                                                     const _Float16* __restrict__ BT,
                                                     const float* __restrict__ bias,
                                                     _Float16* __restrict__ Qf,
                                                     _Float16* __restrict__ Kf,
                                                     _Float16* __restrict__ VTf,
                                                     float* __restrict__ Out) {
  __shared__ _Float16 sA[128 * 32];
  __shared__ _Float16 sB[128 * 32];
  const int tid = threadIdx.x;
  const int wave = tid >> 6, lane = tid & 63;
  const int quad = lane >> 4, l16 = lane & 15;
  const int m0 = blockIdx.x * 128;
  const int n0 = blockIdx.y * 128;
  const int mw = (wave & 1) * 64, nw = (wave >> 1) * 64;
  const int KD = 1280;

  // DMA source group swizzle: loop-invariant per lane
  const int srcg = (lane & 3) ^ ((lane >> 3) & 3);
  // fragment-read physical group: loop-invariant per lane
  const int rg = (quad ^ ((l16 >> 1) & 3)) * 8;

  f32x4 acc[4][4] = {};

  for (int kt = 0; kt < KD; kt += 32) {
#pragma unroll
    for (int c = 0; c < 2; ++c) {
      const int j = wave * 2 + c;
      const int row = j * 16 + (lane >> 2);
      async16(A + (size_t)(m0 + row) * KD + kt + srcg * 8, &sA[j * 512]);
      async16(BT + (size_t)(n0 + row) * KD + kt + srcg * 8, &sB[j * 512]);
    }
    __syncthreads();
    half8 af[4], bf[4];
#pragma unroll
    for (int i = 0; i < 4; ++i) {
      af[i] = *(const half8*)&sA[(mw + i * 16 + l16) * 32 + rg];
      bf[i] = *(const half8*)&sB[(nw + i * 16 + l16) * 32 + rg];
    }
#pragma unroll
    for (int i = 0; i < 4; ++i)
#pragma unroll
      for (int j2 = 0; j2 < 4; ++j2)
        acc[i][j2] = MFMA(af[i], bf[j2], acc[i][j2]);
    __syncthreads();
  }

  // epilogue: C row = (quad*4+reg), col = l16  [m89-verified]
#pragma unroll
  for (int i = 0; i < 4; ++i) {
#pragma unroll
    for (int j2 = 0; j2 < 4; ++j2) {
      const int col = n0 + nw + j2 * 16 + l16;
      const float bv = bias[col];
      const int rowb = m0 + mw + i * 16 + quad * 4;
#pragma unroll
      for (int r = 0; r < 4; ++r) {
        const float v = acc[i][j2][r] + bv;
        const int mrow = rowb + r;
        if (MODE == 0) {
          const int which = col / 1280;
          const int rem = col - which * 1280;
          const int h = rem / 80;
          const int kk = rem - h * 80;
          const int s = mrow >> 9, l = mrow & 511;
          const int shh = s * 16 + h;
          if (which == 0)
            Qf[((size_t)shh * 512 + l) * 96 + kk] = (_Float16)v;
          else if (which == 1)
            Kf[((size_t)shh * 512 + l) * 96 + kk] = (_Float16)v;
          else
            VTf[((size_t)shh * 80 + kk) * 512 + l] = (_Float16)v;
        } else {
          Out[(size_t)mrow * 1280 + col] = v;
        }
      }
    }
  }
}

// ---------------- RoPE in-place on Qf/Kf + zero the k-pad [80,96) -------------
__global__ __launch_bounds__(256) void rope_k(_Float16* __restrict__ Qf,
                                              _Float16* __restrict__ Kf,
                                              const float* __restrict__ cosNK,
                                              const float* __restrict__ sinNK) {
  const int gid = blockIdx.x * 256 + threadIdx.x;
  const int j = gid & 63;
  const int row = gid >> 6;
  const int qk = row >> 17;
  const int r = row & 131071;      // (s*16+h)*512 + l
  _Float16* buf = qk ? Kf : Qf;
  const int l = r & 511;
  const int s = r >> 13;
  const int t = s * 512 + l;
  const size_t base = (size_t)r * 96;
  if (j < 40) {
    const float v1 = (float)buf[base + j];
    const float v2 = (float)buf[base + j + 40];
    const float c1 = cosNK[t * 80 + j], s1 = sinNK[t * 80 + j];
    const float c2 = cosNK[t * 80 + j + 40], s2 = sinNK[t * 80 + j + 40];
    buf[base + j] = (_Float16)(v1 * c1 - v2 * s1);
    buf[base + j + 40] = (_Float16)(v2 * c2 + v1 * s2);
  } else if (j < 56) {
    buf[base + 40 + j] = (_Float16)0.f;  // kk = 80..95
  }
}

// ---------------- flash attention (S^T form, no-max softmax, sum via ones) ----
// block = (seg-head, 64-row q tile): 4 waves x 16 rows. BC=64, dim 80 (pad 96).
__global__ __launch_bounds__(256) void attn_k(const _Float16* __restrict__ Qf,
                                              const _Float16* __restrict__ Kf,
                                              const _Float16* __restrict__ VTf,
                                              _Float16* __restrict__ attnA) {
  __shared__ _Float16 sP[64 * 72];    // P tile, row stride 72
  __shared__ _Float16 sK[64 * 104];   // K tile, row stride 104 (conflict-free)
  __shared__ _Float16 sV[96 * 72];    // rows 0..79: V^T tile; rows 80..95: ones
  const int tid = threadIdx.x;
  const int wave = tid >> 6, lane = tid & 63;
  const int quad = lane >> 4, l16 = lane & 15;
  const int shh = blockIdx.x;  // s*16+h
  const int qt = blockIdx.y;   // 0..7 (64-row q tiles)
  const int h = shh & 15;
  const int s = shh >> 4;

  const _Float16* Qb = Qf + ((size_t)shh * 512 + qt * 64) * 96;
  const _Float16* Kb0 = Kf + (size_t)shh * 512 * 96;
  const _Float16* Vb0 = VTf + (size_t)shh * 80 * 512;

  // Q fragments straight from global (rows are lane-exact), pre-scaled
  const _Float16 c1h = (_Float16)(ATT_SCALE * LOG2E);
  half8 qf[3];
#pragma unroll
  for (int ks = 0; ks < 3; ++ks) {
    half8 t = *(const half8*)(Qb + (size_t)(wave * 16 + l16) * 96 + ks * 32 + quad * 8);
#pragma unroll
    for (int e = 0; e < 8; ++e) t[e] *= c1h;
    qf[ks] = t;
  }

  // ones rows for the row-sum trick
  for (int idx = tid; idx < 16 * 72; idx += 256) sV[80 * 72 + idx] = (_Float16)1.f;

  f32x4 o[6] = {};  // ft 0..4: output features; ft 5: row sum

  for (int kc = 0; kc < 8; ++kc) {
    __syncthreads();  // prev iter LDS reads done (iter0: ones visible)
    // K tile -> sK, padded stride 104 halves (208 B), masked DMA (13 chunks)
    const _Float16* Kb = Kb0 + (size_t)kc * 64 * 96;
#pragma unroll
    for (int c = 0; c < 4; ++c) {
      const int j = wave + 4 * c;
      if (j < 13) {
        const int off = j * 1024 + lane * 16;  // LDS byte offset
        const int krow = off / 208;
        const int kcol = off - krow * 208;     // bytes within padded row
        if (kcol < 192)
          async16(Kb + (size_t)krow * 96 + (kcol >> 1), &sK[j * 512]);
      }
    }
    // V^T tile -> sV, padded stride 72 halves (144 B), masked DMA (12 chunks)
#pragma unroll
    for (int c = 0; c < 3; ++c) {
      const int j = wave + 4 * c;
      const int off = j * 1024 + lane * 16;
      const int vrow = off / 144;
      const int colb = off - vrow * 144;
      if (vrow < 80 && colb < 128)
        async16(Vb0 + (size_t)vrow * 512 + kc * 64 + (colb >> 1), &sV[j * 512]);
    }
    __syncthreads();

    // S^T = K Q^T (operand swap): lane holds S[q=l16][k=mt*16+quad*4+r]
    f32x4 sacc[4] = {};
#pragma unroll
    for (int mt = 0; mt < 4; ++mt) {
#pragma unroll
      for (int ks = 0; ks < 3; ++ks) {
        half8 kb = *(const half8*)&sK[(mt * 16 + l16) * 104 + ks * 32 + quad * 8];
        sacc[mt] = MFMA(kb, qf[ks], sacc[mt]);
      }
    }

    // p = exp2(s), packed pairs (consecutive k!), one b64 store per mt
#pragma unroll
    for (int mt = 0; mt < 4; ++mt) {
      union { fp16x2 h2[2]; half4v h4; } u;
      u.h2[0] = __builtin_amdgcn_cvt_pkrtz(
          __builtin_amdgcn_exp2f(sacc[mt][0]),
          __builtin_amdgcn_exp2f(sacc[mt][1]));
      u.h2[1] = __builtin_amdgcn_cvt_pkrtz(
          __builtin_amdgcn_exp2f(sacc[mt][2]),
          __builtin_amdgcn_exp2f(sacc[mt][3]));
      *(half4v*)&sP[(wave * 16 + l16) * 72 + mt * 16 + quad * 4] = u.h4;
    }
    // sP rows are wave-private: per-wave LDS ordering suffices, no barrier

    // O += P V  (ft=5 accumulates the row sum via the ones rows)
#pragma unroll
    for (int ks = 0; ks < 2; ++ks) {
      half8 pa = *(const half8*)&sP[(wave * 16 + l16) * 72 + ks * 32 + quad * 8];
#pragma unroll
      for (int ft = 0; ft < 6; ++ft) {
        half8 vb = *(const half8*)&sV[(ft * 16 + l16) * 72 + ks * 32 + quad * 8];
        o[ft] = MFMA(pa, vb, o[ft]);
      }
    }
  }

  // epilogue: divide by row sum, store fp16 into attnA [token][h*80+f]
#pragma unroll
  for (int r = 0; r < 4; ++r) {
    const float inv = 1.0f / o[5][r];
    const int token = s * 512 + qt * 64 + wave * 16 + quad * 4 + r;
#pragma unroll
    for (int ft = 0; ft < 5; ++ft)
      attnA[(size_t)token * 1280 + h * 80 + ft * 16 + l16] =
          (_Float16)(o[ft][r] * inv);
  }
}

extern "C" void kernel_launch(void* const* d_in, const int* in_sizes, int n_in,
                              void* d_out, int out_size, void* d_ws, size_t ws_size,
                              hipStream_t stream) {
  (void)in_sizes; (void)n_in; (void)out_size; (void)ws_size;
  const float* hidden = (const float*)d_in[0];
  const float* cosNK = (const float*)d_in[2];
  const float* sinNK = (const float*)d_in[3];
  const float* qkv_w = (const float*)d_in[4];
  const float* qkv_b = (const float*)d_in[5];
  const float* proj_w = (const float*)d_in[6];
  const float* proj_b = (const float*)d_in[7];
  float* out = (float*)d_out;

  char* ws = (char*)d_ws;
  _Float16* hA    = (_Float16*)(ws);                   // 8192x1280        20971520 B
  _Float16* wT    = (_Float16*)(ws + 20971520);        // 3840x1280         9830400 B
  _Float16* projT = (_Float16*)(ws + 30801920);        // 1280x1280         3276800 B
  _Float16* Qf    = (_Float16*)(ws + 34078720);        // 256x512x96       25165824 B
  _Float16* Kf    = (_Float16*)(ws + 59244544);        // 256x512x96       25165824 B
  _Float16* VTf   = (_Float16*)(ws + 84410368);        // 256x80x512       20971520 B
  _Float16* attnA = (_Float16*)(ws + 105381888);       // 8192x1280        20971520 B

  cvt_k<<<10240, 256, 0, stream>>>(hidden, hA, 2621440);
  transpose_cvt_k<<<dim3(120, 40), 256, 0, stream>>>(qkv_w, wT, 1280, 3840);
  transpose_cvt_k<<<dim3(40, 40), 256, 0, stream>>>(proj_w, projT, 1280, 1280);
  gemm_k<0, 4><<<dim3(64, 30), 256, 0, stream>>>(hA, wT, qkv_b, Qf, Kf, VTf, nullptr);
  rope_k<<<65536, 256, 0, stream>>>(Qf, Kf, cosNK, sinNK);
  attn_k<<<dim3(256, 8), 256, 0, stream>>>(Qf, Kf, VTf, attnA);
  gemm_k<1, 1><<<dim3(64, 10), 256, 0, stream>>>(attnA, projT, proj_b, nullptr,
                                                 nullptr, nullptr, out);
}